// Round 1
// baseline (938.818 us; speedup 1.0000x reference)
//
#include <hip/hip_runtime.h>
#include <hip/hip_bf16.h>

#define NEGV (-10000.0f)
constexpr int B_ = 32, S_ = 256, D_ = 512, K_ = 8, L_ = 64;

// ---------------------------------------------------------------------------
// Kernel 1: W2[k][h][i][l] = sum_d conv_w[k][d][i][h] * cls_w[l][d]
// grid (8 i-tiles, 8 h, 8 k), block 256. Skips h>k blocks.
// ---------------------------------------------------------------------------
__global__ __launch_bounds__(256) void w2_kernel(const float* __restrict__ conv_w,
                                                 const float* __restrict__ cls_w,
                                                 float* __restrict__ W2) {
  const int h = blockIdx.y, k = blockIdx.z;
  if (h > k) return;
  const int i0 = blockIdx.x * 64;
  __shared__ __align__(16) float As[32 * 64];  // [d'][i']
  __shared__ __align__(16) float Bs[32 * 65];  // [d'][l] padded
  const int tid = threadIdx.x;
  float acc[16];
#pragma unroll
  for (int q = 0; q < 16; q++) acc[q] = 0.f;
  const int tr = tid >> 4, tc = tid & 15;
  for (int d0 = 0; d0 < D_; d0 += 32) {
#pragma unroll
    for (int q = 0; q < 8; q++) {
      const int dd = tid >> 3;           // 0..31
      const int ii = (tid & 7) * 8 + q;  // 0..63
      As[dd * 64 + ii] = conv_w[(size_t)((k * D_ + d0 + dd) * D_ + i0 + ii) * 8 + h];
      const int ll = tid >> 2;           // 0..63
      const int d2 = (tid & 3) * 8 + q;  // 0..31
      Bs[d2 * 65 + ll] = cls_w[ll * D_ + d0 + d2];
    }
    __syncthreads();
#pragma unroll 4
    for (int kk = 0; kk < 32; kk++) {
      float a[4], bb[4];
#pragma unroll
      for (int r = 0; r < 4; r++) a[r] = As[kk * 64 + tr * 4 + r];
#pragma unroll
      for (int c = 0; c < 4; c++) bb[c] = Bs[kk * 65 + tc * 4 + c];
#pragma unroll
      for (int r = 0; r < 4; r++)
#pragma unroll
        for (int c = 0; c < 4; c++) acc[r * 4 + c] += a[r] * bb[c];
    }
    __syncthreads();
  }
#pragma unroll
  for (int r = 0; r < 4; r++) {
    const int i = i0 + tr * 4 + r;
#pragma unroll
    for (int c = 0; c < 4; c++) {
      const int l = tc * 4 + c;
      W2[((size_t)(k * 8 + h) * D_ + i) * 64 + l] = acc[r * 4 + c];
    }
  }
}

// ---------------------------------------------------------------------------
// Kernel 1b: bias2[k][l] = cls_b[l] + sum_d conv_b[k][d] * cls_w[l][d]
// ---------------------------------------------------------------------------
__global__ void bias2_kernel(const float* __restrict__ conv_b, const float* __restrict__ cls_w,
                             const float* __restrict__ cls_b, float* __restrict__ bias2) {
  const int idx = blockIdx.x * 256 + threadIdx.x;  // 0..511
  const int k = idx >> 6, l = idx & 63;
  float s = cls_b[l];
  for (int d = 0; d < D_; d++) s += conv_b[k * D_ + d] * cls_w[l * D_ + d];
  bias2[idx] = s;
}

// ---------------------------------------------------------------------------
// Kernel 2: LS[b][t][k][l] = bias2[k][l]
//             + sum_{j=0..(k+1)*512-1} word_rep_flat[(b*S+t-k)*D + j] * W2[k][j][l]
// masked to NEGV when l==0 || t<k || mask[b,t]!=1.
// Windowed GEMM: BM=128 rows(t), BN=64 (all L), BK=16. grid (k=8, mtile=64).
// ---------------------------------------------------------------------------
__global__ __launch_bounds__(256) void ls_kernel(const float* __restrict__ wr,
                                                 const int* __restrict__ mask,
                                                 const float* __restrict__ W2,
                                                 const float* __restrict__ bias2,
                                                 float* __restrict__ LS) {
  const int k = blockIdx.x;
  const int m0 = blockIdx.y * 128;
  const int b = m0 >> 8, t0 = m0 & 255;
  const int tid = threadIdx.x;
  __shared__ __align__(16) float As[128 * 16];  // [row][j]
  __shared__ __align__(16) float Bs[16 * 64];   // [j][l]
  float acc[32];
#pragma unroll
  for (int q = 0; q < 32; q++) acc[q] = 0.f;
  const int tr = tid >> 4, tc = tid & 15;  // rows tr+16r, cols tc*4+c
  const int Kd = (k + 1) * D_;
  const float* wbase = wr + (size_t)b * S_ * D_;
  const float* w2k = W2 + (size_t)k * 8 * D_ * 64;
  for (int j0 = 0; j0 < Kd; j0 += 16) {
#pragma unroll
    for (int q = 0; q < 2; q++) {
      const int id = tid + q * 256;
      const int row = id >> 2, c4 = id & 3;
      const int t = t0 + row;
      const int rb = (t - k < 0) ? 0 : (t - k);  // clamp: garbage rows masked at store
      const float4 v = *(const float4*)(wbase + (size_t)rb * D_ + j0 + c4 * 4);
      *(float4*)(&As[row * 16 + c4 * 4]) = v;
    }
    {
      const int row = tid >> 4, c4 = tid & 15;
      const float4 v = *(const float4*)(w2k + (size_t)(j0 + row) * 64 + c4 * 4);
      *(float4*)(&Bs[row * 64 + c4 * 4]) = v;
    }
    __syncthreads();
#pragma unroll
    for (int kk = 0; kk < 16; kk++) {
      float a[8], bb[4];
#pragma unroll
      for (int r = 0; r < 8; r++) a[r] = As[(tr + 16 * r) * 16 + kk];
#pragma unroll
      for (int c = 0; c < 4; c++) bb[c] = Bs[kk * 64 + tc * 4 + c];
#pragma unroll
      for (int r = 0; r < 8; r++)
#pragma unroll
        for (int c = 0; c < 4; c++) acc[r * 4 + c] += a[r] * bb[c];
    }
    __syncthreads();
  }
#pragma unroll
  for (int r = 0; r < 8; r++) {
    const int row = tr + 16 * r;
    const int t = t0 + row;
    const bool valid = (t >= k) && (mask[b * S_ + t] == 1);
    float vv[4];
#pragma unroll
    for (int c = 0; c < 4; c++) {
      const int l = tc * 4 + c;
      float v = acc[r * 4 + c] + bias2[k * 64 + l];
      if (!valid || l == 0) v = NEGV;
      vv[c] = v;
    }
    float4 o;
    o.x = vv[0]; o.y = vv[1]; o.z = vv[2]; o.w = vv[3];
    *(float4*)(&LS[((size_t)(b * S_ + t) * 8 + k) * 64 + tc * 4]) = o;
  }
}

// ---------------------------------------------------------------------------
// Kernel 4: semi-CRF DP. One block per batch element, 256 threads.
//   A_t[l]   = LSE_k row_t[k,l]
//   M_u[l]   = LSE_lp(T[l,lp] + A_u[lp])   (via expT matvec, one per step)
//   row_t[k,l] = k>t ? NEG : k==t ? LS+T_FB[l] : LS + M_{t-1-k}[l]
// Stores all M_u to global for the final gather.
// ---------------------------------------------------------------------------
__global__ __launch_bounds__(256) void dp_kernel(const float* __restrict__ T,
                                                 const float* __restrict__ Tfb_g,
                                                 const float* __restrict__ LS,
                                                 float* __restrict__ Mg) {
  const int b = blockIdx.x, tid = threadIdx.x;
  __shared__ float expT[64 * 65];
  __shared__ float Tfb[64];
  __shared__ float Mbuf[8 * 64];
  __shared__ float Abuf[64];
  __shared__ float ebuf[64];
  __shared__ float red[4 * 64];
  __shared__ float rowbuf[8 * 64];
  for (int i = tid; i < 4096; i += 256) expT[(i >> 6) * 65 + (i & 63)] = __expf(T[i]);
  if (tid < 64) Tfb[tid] = Tfb_g[tid];
  __syncthreads();
  const int l6 = tid & 63, cc = tid >> 6;
  const int kk = tid >> 5, lh = tid & 31;
  for (int t = 0; t < S_; t++) {
    // prefetch this step's LS (independent of phase 1 -> hides latency)
    const size_t lsbase = ((size_t)(b * S_ + t) * 8 + kk) * 64 + lh;
    const float ls0 = LS[lsbase];
    const float ls1 = LS[lsbase + 32];
    if (t > 0) {
      const float av = Abuf[l6];
      float mv = av;
#pragma unroll
      for (int off = 32; off > 0; off >>= 1) mv = fmaxf(mv, __shfl_xor(mv, off));
      if (tid < 64) ebuf[tid] = __expf(av - mv);
      __syncthreads();
      float p = 0.f;
#pragma unroll
      for (int j = 0; j < 16; j++) p += expT[l6 * 65 + cc * 16 + j] * ebuf[cc * 16 + j];
      red[cc * 64 + l6] = p;
      __syncthreads();
      if (tid < 64) {
        const float s = red[tid] + red[64 + tid] + red[128 + tid] + red[192 + tid];
        const float Mv = (s > 0.f) ? (__logf(s) + mv) : -1e30f;
        Mbuf[((t - 1) & 7) * 64 + tid] = Mv;
        Mg[((size_t)b * S_ + (t - 1)) * 64 + tid] = Mv;
      }
      __syncthreads();
    }
    {
      float r0, r1;
      if (kk > t) {
        r0 = NEGV; r1 = NEGV;
      } else if (kk == t) {
        r0 = ls0 + Tfb[lh]; r1 = ls1 + Tfb[lh + 32];
      } else {
        const int u = (t - 1 - kk) & 7;
        r0 = ls0 + Mbuf[u * 64 + lh];
        r1 = ls1 + Mbuf[u * 64 + lh + 32];
      }
      rowbuf[kk * 64 + lh] = r0;
      rowbuf[kk * 64 + lh + 32] = r1;
    }
    __syncthreads();
    if (tid < 64) {
      float m = rowbuf[tid];
#pragma unroll
      for (int k2 = 1; k2 < 8; k2++) m = fmaxf(m, rowbuf[k2 * 64 + tid]);
      float s = 0.f;
#pragma unroll
      for (int k2 = 0; k2 < 8; k2++) s += __expf(rowbuf[k2 * 64 + tid] - m);
      Abuf[tid] = (s > 0.f) ? (__logf(s) + m) : -1e30f;
    }
    __syncthreads();
  }
}

// ---------------------------------------------------------------------------
// Kernel 5: final gather.
// out[b] = LSE_{k,l}( row_{len-1-k}[b,k,l] + T_to_END[l] ),
// row recomputed from LS + Mg. One wave per b.
// ---------------------------------------------------------------------------
__global__ __launch_bounds__(64) void final_kernel(const int* __restrict__ mask,
                                                   const float* __restrict__ Tfb_g,
                                                   const float* __restrict__ T2e_g,
                                                   const float* __restrict__ LS,
                                                   const float* __restrict__ Mg,
                                                   float* __restrict__ out) {
  const int b = blockIdx.x, lane = threadIdx.x;
  int lenp = 0;
  for (int s = lane; s < S_; s += 64) lenp += (mask[b * S_ + s] == 1) ? 1 : 0;
#pragma unroll
  for (int off = 32; off > 0; off >>= 1) lenp += __shfl_xor(lenp, off);
  const int len = lenp;
  const float t2e = T2e_g[lane];
  float vals[8];
  float mx = -3.4e38f;
#pragma unroll
  for (int k = 0; k < 8; k++) {
    int tk = len - 1 - k;
    if (tk < 0) tk = S_ - 1;
    float g;
    if (k > tk) {
      g = NEGV;
    } else {
      const float ls = LS[((size_t)(b * S_ + tk) * 8 + k) * 64 + lane];
      if (k == tk) g = ls + Tfb_g[lane];
      else g = (mask[b * S_ + tk] == 1)
                   ? (ls + Mg[((size_t)b * S_ + (tk - 1 - k)) * 64 + lane])
                   : NEGV;
    }
    const float v = g + t2e;
    vals[k] = v;
    mx = fmaxf(mx, v);
  }
#pragma unroll
  for (int off = 32; off > 0; off >>= 1) mx = fmaxf(mx, __shfl_xor(mx, off));
  float s = 0.f;
#pragma unroll
  for (int k = 0; k < 8; k++) s += __expf(vals[k] - mx);
#pragma unroll
  for (int off = 32; off > 0; off >>= 1) s += __shfl_xor(s, off);
  if (lane == 0) out[b] = __logf(s) + mx;
}

// ---------------------------------------------------------------------------
extern "C" void kernel_launch(void* const* d_in, const int* in_sizes, int n_in,
                              void* d_out, int out_size, void* d_ws, size_t ws_size,
                              hipStream_t stream) {
  const float* wr     = (const float*)d_in[0];  // (32,256,512)
  const int*   mask   = (const int*)d_in[1];    // (32,256)
  const float* conv_w = (const float*)d_in[2];  // (8,512,512,8)
  const float* conv_b = (const float*)d_in[3];  // (8,512)
  const float* cls_w  = (const float*)d_in[4];  // (64,512)
  const float* cls_b  = (const float*)d_in[5];  // (64,)
  const float* T      = (const float*)d_in[6];  // (64,64)
  const float* Tfb    = (const float*)d_in[7];  // (64,)
  const float* T2e    = (const float*)d_in[8];  // (64,)
  float* out = (float*)d_out;

  float* ws = (float*)d_ws;
  float* W2    = ws;             // [8][8][512][64] = 2,097,152 floats
  float* bias2 = ws + 2097152;   // [8][64]         = 512
  float* LS    = ws + 2097664;   // [32][256][8][64]= 4,194,304
  float* Mg    = ws + 6291968;   // [32][256][64]   = 524,288
  // total 6,816,256 floats = 27.3 MB

  w2_kernel<<<dim3(8, 8, 8), 256, 0, stream>>>(conv_w, cls_w, W2);
  bias2_kernel<<<2, 256, 0, stream>>>(conv_b, cls_w, cls_b, bias2);
  ls_kernel<<<dim3(8, 64), 256, 0, stream>>>(wr, mask, W2, bias2, LS);
  dp_kernel<<<32, 256, 0, stream>>>(T, Tfb, LS, Mg);
  final_kernel<<<32, 64, 0, stream>>>(mask, Tfb, T2e, LS, Mg, out);
}

// Round 2
// 601.765 us; speedup vs baseline: 1.5601x; 1.5601x over previous
//
#include <hip/hip_runtime.h>
#include <hip/hip_bf16.h>

#define NEGV (-10000.0f)
constexpr int B_ = 32, S_ = 256, D_ = 512, K_ = 8, L_ = 64;

typedef __bf16 bf16_t;
typedef bf16_t bf16x8 __attribute__((ext_vector_type(8)));
typedef float f32x4 __attribute__((ext_vector_type(4)));

// ---------------------------------------------------------------------------
// cast word_rep (fp32, 32*256*512) -> bf16 A matrix [8192][512]
// ---------------------------------------------------------------------------
__global__ __launch_bounds__(256) void cast_kernel(const float* __restrict__ wr,
                                                   bf16_t* __restrict__ Awr) {
  const int i = (blockIdx.x * 256 + threadIdx.x) * 8;
  const float4 a = *(const float4*)(wr + i);
  const float4 b = *(const float4*)(wr + i + 4);
  bf16x8 o;
  o[0] = (bf16_t)a.x; o[1] = (bf16_t)a.y; o[2] = (bf16_t)a.z; o[3] = (bf16_t)a.w;
  o[4] = (bf16_t)b.x; o[5] = (bf16_t)b.y; o[6] = (bf16_t)b.z; o[7] = (bf16_t)b.w;
  *(bf16x8*)(Awr + i) = o;
}

// ---------------------------------------------------------------------------
// Kernel 1: Vt[(k*64+l)][(o*512+i)] = (k>=o) ? sum_d conv_w[k][d][i][k-o] * cls_w[l][d] : 0
// stored bf16, B^T layout [N=512][K=4096]. grid (8 i-tiles, 8 h, 8 k).
// h>k blocks write the zero region o=h (>k).
// ---------------------------------------------------------------------------
__global__ __launch_bounds__(256) void w2_kernel(const float* __restrict__ conv_w,
                                                 const float* __restrict__ cls_w,
                                                 bf16_t* __restrict__ Vt) {
  const int h = blockIdx.y, k = blockIdx.z;
  const int i0 = blockIdx.x * 64;
  const int tid = threadIdx.x;
  if (h > k) {  // zero-fill Vt rows k*64+l, col block h*512+i0..+63
    uint4 z; z.x = z.y = z.z = z.w = 0u;
#pragma unroll
    for (int q = 0; q < 2; q++) {
      const int c = tid + q * 256;
      const int l = c >> 3, cc = c & 7;
      *(uint4*)(Vt + (size_t)(k * 64 + l) * 4096 + h * 512 + i0 + cc * 8) = z;
    }
    return;
  }
  __shared__ __align__(16) float As[32 * 64];   // [d'][i']
  __shared__ __align__(16) float Bs[32 * 65];   // [d'][l] padded
  __shared__ __align__(16) bf16_t Ls2[64 * 72]; // [l][i] padded
  float acc[16];
#pragma unroll
  for (int q = 0; q < 16; q++) acc[q] = 0.f;
  const int tr = tid >> 4, tc = tid & 15;
  for (int d0 = 0; d0 < D_; d0 += 32) {
#pragma unroll
    for (int q = 0; q < 8; q++) {
      const int dd = tid >> 3;
      const int ii = (tid & 7) * 8 + q;
      As[dd * 64 + ii] = conv_w[(size_t)((k * D_ + d0 + dd) * D_ + i0 + ii) * 8 + h];
      const int ll = tid >> 2;
      const int d2 = (tid & 3) * 8 + q;
      Bs[d2 * 65 + ll] = cls_w[ll * D_ + d0 + d2];
    }
    __syncthreads();
#pragma unroll 4
    for (int kk = 0; kk < 32; kk++) {
      float a[4], bb[4];
#pragma unroll
      for (int r = 0; r < 4; r++) a[r] = As[kk * 64 + tr * 4 + r];
#pragma unroll
      for (int c = 0; c < 4; c++) bb[c] = Bs[kk * 65 + tc * 4 + c];
#pragma unroll
      for (int r = 0; r < 4; r++)
#pragma unroll
        for (int c = 0; c < 4; c++) acc[r * 4 + c] += a[r] * bb[c];
    }
    __syncthreads();
  }
  // acc[r][c]: i = i0+tr*4+r, l = tc*4+c  -> stage transposed [l][i] as bf16
#pragma unroll
  for (int r = 0; r < 4; r++)
#pragma unroll
    for (int c = 0; c < 4; c++)
      Ls2[(tc * 4 + c) * 72 + tr * 4 + r] = (bf16_t)acc[r * 4 + c];
  __syncthreads();
  const int o = k - h;
#pragma unroll
  for (int q = 0; q < 2; q++) {
    const int c = tid + q * 256;
    const int l = c >> 3, cc = c & 7;
    const uint4 v = *(const uint4*)(&Ls2[l * 72 + cc * 8]);
    *(uint4*)(Vt + (size_t)(k * 64 + l) * 4096 + o * 512 + i0 + cc * 8) = v;
  }
}

// ---------------------------------------------------------------------------
// Kernel 1b: bias2[k][l] = cls_b[l] + sum_d conv_b[k][d] * cls_w[l][d]
// ---------------------------------------------------------------------------
__global__ void bias2_kernel(const float* __restrict__ conv_b, const float* __restrict__ cls_w,
                             const float* __restrict__ cls_b, float* __restrict__ bias2) {
  const int idx = blockIdx.x * 256 + threadIdx.x;
  const int k = idx >> 6, l = idx & 63;
  float s = cls_b[l];
  for (int d = 0; d < D_; d++) s += conv_b[k * D_ + d] * cls_w[l * D_ + d];
  bias2[idx] = s;
}

// ---------------------------------------------------------------------------
// Kernel 2: LS = windowed GEMM via MFMA bf16.
// C[m][n] = sum_{o,i} Awr[m-o][i] * Vt[n][o*512+i],  m=b*256+t, n=k*64+l
// BM=128 BN=128 BK=32, 4 waves each 64x64. Epilogue: +bias2, NEGV masking.
// ---------------------------------------------------------------------------
__global__ __launch_bounds__(256) void ls_mfma(const bf16_t* __restrict__ Awr,
                                               const bf16_t* __restrict__ Vt,
                                               const float* __restrict__ bias2,
                                               const int* __restrict__ mask,
                                               float* __restrict__ LS) {
  constexpr int LDA = 40;  // padded row stride (elems): 80B -> 2-way-only conflicts
  __shared__ __align__(16) bf16_t As[128 * LDA];
  __shared__ __align__(16) bf16_t Bs[128 * LDA];
  const int tid = threadIdx.x;
  const int m0 = blockIdx.x * 128, n0 = blockIdx.y * 128;
  const int w = tid >> 6, lane = tid & 63;
  const int wm = w & 1, wn = w >> 1;
  const int lrow = lane & 15, quad = lane >> 4;

  f32x4 acc[4][4] = {};
  for (int kt = 0; kt < 128; kt++) {
    const int j0 = kt * 32;
    const int o = j0 >> 9;
#pragma unroll
    for (int q = 0; q < 2; q++) {
      const int c = tid + q * 256;  // 0..511 chunks of 16B
      const int row = c >> 2, cc = c & 3;
      int src = m0 + row - o;
      if (src < 0) src = 0;  // garbage row 0: feeds only zero-weights or masked outputs
      const uint4 va = *(const uint4*)(Awr + (size_t)src * 512 + (j0 & 511) + cc * 8);
      *(uint4*)(&As[row * LDA + cc * 8]) = va;
      const uint4 vb = *(const uint4*)(Vt + (size_t)(n0 + row) * 4096 + j0 + cc * 8);
      *(uint4*)(&Bs[row * LDA + cc * 8]) = vb;
    }
    __syncthreads();
    bf16x8 af[4], bfr[4];
#pragma unroll
    for (int mi = 0; mi < 4; mi++)
      af[mi] = *(const bf16x8*)(&As[(wm * 64 + mi * 16 + lrow) * LDA + quad * 8]);
#pragma unroll
    for (int ni = 0; ni < 4; ni++)
      bfr[ni] = *(const bf16x8*)(&Bs[(wn * 64 + ni * 16 + lrow) * LDA + quad * 8]);
#pragma unroll
    for (int mi = 0; mi < 4; mi++)
#pragma unroll
      for (int ni = 0; ni < 4; ni++)
        acc[mi][ni] = __builtin_amdgcn_mfma_f32_16x16x32_bf16(af[mi], bfr[ni], acc[mi][ni], 0, 0, 0);
    __syncthreads();
  }
  // epilogue
  float bn[4];
  int kcol[4], lcol[4];
#pragma unroll
  for (int ni = 0; ni < 4; ni++) {
    const int n = n0 + wn * 64 + ni * 16 + lrow;
    bn[ni] = bias2[n];
    kcol[ni] = n >> 6;
    lcol[ni] = n & 63;
  }
#pragma unroll
  for (int mi = 0; mi < 4; mi++) {
#pragma unroll
    for (int d = 0; d < 4; d++) {
      const int m = m0 + wm * 64 + mi * 16 + quad * 4 + d;
      const int t = m & 255;
      const bool mok = (mask[m] == 1);
#pragma unroll
      for (int ni = 0; ni < 4; ni++) {
        const int n = n0 + wn * 64 + ni * 16 + lrow;
        float v = acc[mi][ni][d] + bn[ni];
        if (!mok || t < kcol[ni] || lcol[ni] == 0) v = NEGV;
        LS[(size_t)m * 512 + n] = v;
      }
    }
  }
}

// ---------------------------------------------------------------------------
// Kernel 3: semi-CRF DP, ONE WAVE per batch element. Lane = label l.
//   expT row and 8-deep M history live in registers; only e[] crosses lanes.
// ---------------------------------------------------------------------------
__global__ __launch_bounds__(64) void dp_kernel(const float* __restrict__ T,
                                                const float* __restrict__ Tfb_g,
                                                const float* __restrict__ LS,
                                                float* __restrict__ Mg) {
  const int b = blockIdx.x, l = threadIdx.x;
  float rowT[64];
#pragma unroll
  for (int j = 0; j < 64; j++) rowT[j] = __expf(T[l * 64 + j]);
  const float tfb = Tfb_g[l];
  __shared__ __align__(16) float eb[2][64];
  float Mh[8];
#pragma unroll
  for (int u = 0; u < 8; u++) Mh[u] = NEGV;
  float A = 0.f;
  const float* lsb = LS + (size_t)b * 256 * 512 + l;
  float ls[8];
#pragma unroll
  for (int k = 0; k < 8; k++) ls[k] = lsb[k * 64];
  for (int t = 0; t < 256; t++) {
    float lsc[8];
#pragma unroll
    for (int k = 0; k < 8; k++) lsc[k] = ls[k];
    if (t < 255) {
      const float* p = lsb + (size_t)(t + 1) * 512;
#pragma unroll
      for (int k = 0; k < 8; k++) ls[k] = p[k * 64];
    }
    if (t > 0) {
      // M_{t-1}[l] = LSE_j(T[l][j] + A_{t-1}[j])
      float mx = A;
#pragma unroll
      for (int off = 32; off > 0; off >>= 1) mx = fmaxf(mx, __shfl_xor(mx, off));
      eb[t & 1][l] = __expf(A - mx);
      __syncthreads();
      float p = 0.f;
#pragma unroll
      for (int j4 = 0; j4 < 16; j4++) {
        const float4 e4 = *(const float4*)(&eb[t & 1][j4 * 4]);
        p += rowT[j4 * 4 + 0] * e4.x + rowT[j4 * 4 + 1] * e4.y +
             rowT[j4 * 4 + 2] * e4.z + rowT[j4 * 4 + 3] * e4.w;
      }
      const float Mv = (p > 0.f) ? (__logf(p) + mx) : -1e30f;
      Mh[(t - 1) & 7] = Mv;
      Mg[((size_t)b * 256 + (t - 1)) * 64 + l] = Mv;
    }
    // row_t[k][l] and A_t[l] = LSE_k
    float r[8];
    float mr = -3.4e38f;
#pragma unroll
    for (int k = 0; k < 8; k++) {
      float v;
      if (k > t) v = NEGV;
      else if (k == t) v = lsc[k] + tfb;
      else v = lsc[k] + Mh[(t - 1 - k) & 7];
      r[k] = v;
      mr = fmaxf(mr, v);
    }
    float s = 0.f;
#pragma unroll
    for (int k = 0; k < 8; k++) s += __expf(r[k] - mr);
    A = (s > 0.f) ? (__logf(s) + mr) : -1e30f;
  }
}

// ---------------------------------------------------------------------------
// Kernel 4: final gather (one wave per b).
// ---------------------------------------------------------------------------
__global__ __launch_bounds__(64) void final_kernel(const int* __restrict__ mask,
                                                   const float* __restrict__ Tfb_g,
                                                   const float* __restrict__ T2e_g,
                                                   const float* __restrict__ LS,
                                                   const float* __restrict__ Mg,
                                                   float* __restrict__ out) {
  const int b = blockIdx.x, lane = threadIdx.x;
  int lenp = 0;
  for (int s = lane; s < S_; s += 64) lenp += (mask[b * S_ + s] == 1) ? 1 : 0;
#pragma unroll
  for (int off = 32; off > 0; off >>= 1) lenp += __shfl_xor(lenp, off);
  const int len = lenp;
  const float t2e = T2e_g[lane];
  float vals[8];
  float mx = -3.4e38f;
#pragma unroll
  for (int k = 0; k < 8; k++) {
    int tk = len - 1 - k;
    if (tk < 0) tk = S_ - 1;
    float g;
    if (k > tk) {
      g = NEGV;
    } else {
      const float ls = LS[((size_t)(b * S_ + tk) * 8 + k) * 64 + lane];
      if (k == tk) g = ls + Tfb_g[lane];
      else g = (mask[b * S_ + tk] == 1)
                   ? (ls + Mg[((size_t)b * S_ + (tk - 1 - k)) * 64 + lane])
                   : NEGV;
    }
    const float v = g + t2e;
    vals[k] = v;
    mx = fmaxf(mx, v);
  }
#pragma unroll
  for (int off = 32; off > 0; off >>= 1) mx = fmaxf(mx, __shfl_xor(mx, off));
  float s = 0.f;
#pragma unroll
  for (int k = 0; k < 8; k++) s += __expf(vals[k] - mx);
#pragma unroll
  for (int off = 32; off > 0; off >>= 1) s += __shfl_xor(s, off);
  if (lane == 0) out[b] = __logf(s) + mx;
}

// ---------------------------------------------------------------------------
extern "C" void kernel_launch(void* const* d_in, const int* in_sizes, int n_in,
                              void* d_out, int out_size, void* d_ws, size_t ws_size,
                              hipStream_t stream) {
  const float* wr     = (const float*)d_in[0];  // (32,256,512)
  const int*   mask   = (const int*)d_in[1];    // (32,256)
  const float* conv_w = (const float*)d_in[2];  // (8,512,512,8)
  const float* conv_b = (const float*)d_in[3];  // (8,512)
  const float* cls_w  = (const float*)d_in[4];  // (64,512)
  const float* cls_b  = (const float*)d_in[5];  // (64,)
  const float* T      = (const float*)d_in[6];  // (64,64)
  const float* Tfb    = (const float*)d_in[7];  // (64,)
  const float* T2e    = (const float*)d_in[8];  // (64,)
  float* out = (float*)d_out;

  float* ws = (float*)d_ws;
  bf16_t* Vt    = (bf16_t*)ws;                  // [512][4096] bf16 = 4 MB (1,048,576 f)
  bf16_t* Awr   = (bf16_t*)(ws + 1048576);      // [8192][512] bf16 = 8 MB (2,097,152 f)
  float*  bias2 = ws + 3145728;                 // [8][64] = 512 f
  float*  LS    = ws + 3146240;                 // [8192][512] = 16 MB (4,194,304 f)
  float*  Mg    = ws + 7340544;                 // [32][256][64] = 2 MB (524,288 f)
  // total 7,864,832 floats = 31.5 MB

  cast_kernel<<<2048, 256, 0, stream>>>(wr, Awr);
  w2_kernel<<<dim3(8, 8, 8), 256, 0, stream>>>(conv_w, cls_w, Vt);
  bias2_kernel<<<2, 256, 0, stream>>>(conv_b, cls_w, cls_b, bias2);
  ls_mfma<<<dim3(64, 4), 256, 0, stream>>>(Awr, Vt, bias2, mask, LS);
  dp_kernel<<<32, 64, 0, stream>>>(T, Tfb, LS, Mg);
  final_kernel<<<32, 64, 0, stream>>>(mask, Tfb, T2e, LS, Mg, out);
}

// Round 4
// 503.454 us; speedup vs baseline: 1.8648x; 1.1953x over previous
//
#include <hip/hip_runtime.h>
#include <hip/hip_bf16.h>

#define NEGV (-10000.0f)
constexpr int B_ = 32, S_ = 256, D_ = 512, K_ = 8, L_ = 64;

typedef __bf16 bf16_t;
typedef bf16_t bf16x8 __attribute__((ext_vector_type(8)));
typedef float f32x4 __attribute__((ext_vector_type(4)));

// ---------------------------------------------------------------------------
// cast word_rep (fp32, 32*256*512) -> bf16 A matrix [8192][512]
// ---------------------------------------------------------------------------
__global__ __launch_bounds__(256) void cast_kernel(const float* __restrict__ wr,
                                                   bf16_t* __restrict__ Awr) {
  const int i = (blockIdx.x * 256 + threadIdx.x) * 8;
  const float4 a = *(const float4*)(wr + i);
  const float4 b = *(const float4*)(wr + i + 4);
  bf16x8 o;
  o[0] = (bf16_t)a.x; o[1] = (bf16_t)a.y; o[2] = (bf16_t)a.z; o[3] = (bf16_t)a.w;
  o[4] = (bf16_t)b.x; o[5] = (bf16_t)b.y; o[6] = (bf16_t)b.z; o[7] = (bf16_t)b.w;
  *(bf16x8*)(Awr + i) = o;
}

// ---------------------------------------------------------------------------
// Vt[(k*64+l)][(o*512+i)] = (k>=o) ? sum_d conv_w[k][d][i][k-o] * cls_w[l][d] : 0
// bf16, B^T layout [512][4096]. grid (8 i-tiles, 8 h, 8 k).
// ---------------------------------------------------------------------------
__global__ __launch_bounds__(256) void w2_kernel(const float* __restrict__ conv_w,
                                                 const float* __restrict__ cls_w,
                                                 bf16_t* __restrict__ Vt) {
  const int h = blockIdx.y, k = blockIdx.z;
  const int i0 = blockIdx.x * 64;
  const int tid = threadIdx.x;
  if (h > k) {  // zero-fill region o=h (>k)
    uint4 z; z.x = z.y = z.z = z.w = 0u;
#pragma unroll
    for (int q = 0; q < 2; q++) {
      const int c = tid + q * 256;
      const int l = c >> 3, cc = c & 7;
      *(uint4*)(Vt + (size_t)(k * 64 + l) * 4096 + h * 512 + i0 + cc * 8) = z;
    }
    return;
  }
  __shared__ __align__(16) float As[32 * 64];
  __shared__ __align__(16) float Bs[32 * 65];
  __shared__ __align__(16) bf16_t Ls2[64 * 72];
  float acc[16];
#pragma unroll
  for (int q = 0; q < 16; q++) acc[q] = 0.f;
  const int tr = tid >> 4, tc = tid & 15;
  for (int d0 = 0; d0 < D_; d0 += 32) {
#pragma unroll
    for (int q = 0; q < 8; q++) {
      const int dd = tid >> 3;
      const int ii = (tid & 7) * 8 + q;
      As[dd * 64 + ii] = conv_w[(size_t)((k * D_ + d0 + dd) * D_ + i0 + ii) * 8 + h];
      const int ll = tid >> 2;
      const int d2 = (tid & 3) * 8 + q;
      Bs[d2 * 65 + ll] = cls_w[ll * D_ + d0 + d2];
    }
    __syncthreads();
#pragma unroll 4
    for (int kk = 0; kk < 32; kk++) {
      float a[4], bb[4];
#pragma unroll
      for (int r = 0; r < 4; r++) a[r] = As[kk * 64 + tr * 4 + r];
#pragma unroll
      for (int c = 0; c < 4; c++) bb[c] = Bs[kk * 65 + tc * 4 + c];
#pragma unroll
      for (int r = 0; r < 4; r++)
#pragma unroll
        for (int c = 0; c < 4; c++) acc[r * 4 + c] += a[r] * bb[c];
    }
    __syncthreads();
  }
#pragma unroll
  for (int r = 0; r < 4; r++)
#pragma unroll
    for (int c = 0; c < 4; c++)
      Ls2[(tc * 4 + c) * 72 + tr * 4 + r] = (bf16_t)acc[r * 4 + c];
  __syncthreads();
  const int o = k - h;
#pragma unroll
  for (int q = 0; q < 2; q++) {
    const int c = tid + q * 256;
    const int l = c >> 3, cc = c & 7;
    const uint4 v = *(const uint4*)(&Ls2[l * 72 + cc * 8]);
    *(uint4*)(Vt + (size_t)(k * 64 + l) * 4096 + o * 512 + i0 + cc * 8) = v;
  }
}

// ---------------------------------------------------------------------------
// bias2[k][l] = cls_b[l] + sum_d conv_b[k][d] * cls_w[l][d]
// ---------------------------------------------------------------------------
__global__ void bias2_kernel(const float* __restrict__ conv_b, const float* __restrict__ cls_w,
                             const float* __restrict__ cls_b, float* __restrict__ bias2) {
  const int idx = blockIdx.x * 256 + threadIdx.x;
  const int k = idx >> 6, l = idx & 63;
  float s = cls_b[l];
  for (int d = 0; d < D_; d++) s += conv_b[k * D_ + d] * cls_w[l * D_ + d];
  bias2[idx] = s;
}

// ---------------------------------------------------------------------------
// MFMA GEMM -> ELS = exp(label_score), layout [m=8192][l*8+k].
// Block: 128 m-rows x strip pair (kHi=7-p, kLo=p): (8-p)+(p+1)=9 o-blocks
// = 144 kt-iters, uniform across all 256 blocks. Per strip: 128x64 C-tile,
// 4 waves each 64x32 (acc 4x2). NEGV masking -> els=0.
// ---------------------------------------------------------------------------
__global__ __launch_bounds__(256) void ls_mfma(const bf16_t* __restrict__ Awr,
                                               const bf16_t* __restrict__ Vt,
                                               const float* __restrict__ bias2,
                                               const int* __restrict__ mask,
                                               float* __restrict__ ELS) {
  constexpr int LDA = 40;
  __shared__ __align__(16) bf16_t As[128 * LDA];
  __shared__ __align__(16) bf16_t Bs[64 * LDA];
  const int tid = threadIdx.x;
  const int m0 = blockIdx.x * 128;
  const int p = blockIdx.y;
  const int w = tid >> 6, lane = tid & 63;
  const int wm = w & 1, wn = w >> 1;
  const int lrow = lane & 15, quad = lane >> 4;
  for (int s = 0; s < 2; s++) {
    const int kS = (s == 0) ? (7 - p) : p;
    const int KT = (kS + 1) * 16;
    f32x4 acc[4][2] = {};
    for (int kt = 0; kt < KT; kt++) {
      const int j0 = kt * 32;
      const int o = j0 >> 9;
      // A tile: 128 rows x 32 cols = 512 chunks of 8 bf16
#pragma unroll
      for (int q = 0; q < 2; q++) {
        const int c = tid + q * 256;
        const int row = c >> 2, cc = c & 3;
        int src = m0 + row - o;
        if (src < 0) src = 0;  // garbage feeds only t<k-masked outputs
        const uint4 va = *(const uint4*)(Awr + (size_t)src * 512 + (j0 & 511) + cc * 8);
        *(uint4*)(&As[row * LDA + cc * 8]) = va;
      }
      // B tile: 64 rows x 32 cols = 256 chunks of 8 bf16
      {
        const int br = tid >> 2, bc = tid & 3;
        const uint4 vb = *(const uint4*)(Vt + (size_t)(kS * 64 + br) * 4096 + j0 + bc * 8);
        *(uint4*)(&Bs[br * LDA + bc * 8]) = vb;
      }
      __syncthreads();
      bf16x8 af[4], bfr[2];
#pragma unroll
      for (int mi = 0; mi < 4; mi++)
        af[mi] = *(const bf16x8*)(&As[(wm * 64 + mi * 16 + lrow) * LDA + quad * 8]);
#pragma unroll
      for (int ni = 0; ni < 2; ni++)
        bfr[ni] = *(const bf16x8*)(&Bs[(wn * 32 + ni * 16 + lrow) * LDA + quad * 8]);
#pragma unroll
      for (int mi = 0; mi < 4; mi++)
#pragma unroll
        for (int ni = 0; ni < 2; ni++)
          acc[mi][ni] = __builtin_amdgcn_mfma_f32_16x16x32_bf16(af[mi], bfr[ni], acc[mi][ni], 0, 0, 0);
      __syncthreads();
    }
    // epilogue for strip kS
    float bn[2];
    int lcol[2];
#pragma unroll
    for (int ni = 0; ni < 2; ni++) {
      lcol[ni] = wn * 32 + ni * 16 + lrow;
      bn[ni] = bias2[kS * 64 + lcol[ni]];
    }
#pragma unroll
    for (int mi = 0; mi < 4; mi++) {
#pragma unroll
      for (int d = 0; d < 4; d++) {
        const int m = m0 + wm * 64 + mi * 16 + quad * 4 + d;
        const int t = m & 255;
        const bool mok = (mask[m] == 1);
#pragma unroll
        for (int ni = 0; ni < 2; ni++) {
          const float v = acc[mi][ni][d] + bn[ni];
          const float e = (!mok || t < kS || lcol[ni] == 0) ? 0.f : __expf(v);
          ELS[(size_t)m * 512 + lcol[ni] * 8 + kS] = e;
        }
      }
    }
  }
}

// ---------------------------------------------------------------------------
// Linear-domain semi-CRF DP. One wave per b; lane = label l.
// State: mh[k] = exp(M_{t-1-k} - c_t) (registers, shifted each step);
// BEGIN folds in as phantom slot mh[t]=exp(tfb-c) for t<=7. Per step:
//   e[l] = sum_k els[t][l][k]*mh[k];  m[l] = sum_j expT[l][j]*e[j];
//   S = max_l e; rescale by 1/S; c += log(S).
// Stores m (linear) + c per step for the final gather.
// ---------------------------------------------------------------------------
__global__ __launch_bounds__(64) void dp_kernel(const float* __restrict__ T,
                                                const float* __restrict__ Tfb_g,
                                                const float* __restrict__ ELS,
                                                float* __restrict__ Mg_lin,
                                                float* __restrict__ cs_g) {
  const int b = blockIdx.x, l = threadIdx.x;
  f32x4 rT[16];
#pragma unroll
  for (int j = 0; j < 16; j++) {
    f32x4 r;
#pragma unroll
    for (int q = 0; q < 4; q++) r[q] = __expf(T[l * 64 + j * 4 + q]);
    rT[j] = r;
  }
  __shared__ __align__(16) float eb[2][64];
  float mh[8];
  mh[0] = __expf(Tfb_g[l]);  // BEGIN phantom
#pragma unroll
  for (int u = 1; u < 8; u++) mh[u] = 0.f;
  float c = 0.f;
  const float* ep = ELS + (size_t)b * 256 * 512 + l * 8;
  float4 p0a = *(const float4*)(ep);
  float4 p0b = *(const float4*)(ep + 4);
  float4 p1a = *(const float4*)(ep + 512);
  float4 p1b = *(const float4*)(ep + 516);
  for (int t = 0; t < 256; t++) {
    const float4 ca = p0a, cb = p0b;
    p0a = p1a; p0b = p1b;
    if (t + 2 < 256) {
      p1a = *(const float4*)(ep + (size_t)(t + 2) * 512);
      p1b = *(const float4*)(ep + (size_t)(t + 2) * 512 + 4);
    }
    // e = sum_k els[k] * mh[k]
    float e0 = ca.x * mh[0] + ca.y * mh[1];
    float e1 = ca.z * mh[2] + ca.w * mh[3];
    float e2 = cb.x * mh[4] + cb.y * mh[5];
    float e3 = cb.z * mh[6] + cb.w * mh[7];
    const float e = (e0 + e1) + (e2 + e3);
    eb[t & 1][l] = e;
    float S = e;
#pragma unroll
    for (int off = 32; off > 0; off >>= 1) S = fmaxf(S, __shfl_xor(S, off));
    __syncthreads();
    // matvec m[l] = sum_j expT[l][j] * e[j]
    f32x4 a0 = {0.f, 0.f, 0.f, 0.f}, a1 = a0, a2 = a0, a3 = a0;
    const f32x4* ev = (const f32x4*)(&eb[t & 1][0]);
#pragma unroll
    for (int j = 0; j < 4; j++) {
      a0 += rT[j * 4 + 0] * ev[j * 4 + 0];
      a1 += rT[j * 4 + 1] * ev[j * 4 + 1];
      a2 += rT[j * 4 + 2] * ev[j * 4 + 2];
      a3 += rT[j * 4 + 3] * ev[j * 4 + 3];
    }
    const f32x4 as = (a0 + a1) + (a2 + a3);
    const float m4 = (as[0] + as[1]) + (as[2] + as[3]);
    Mg_lin[((size_t)b * 256 + t) * 64 + l] = m4;
    if (l == 0) cs_g[b * 256 + t] = c;
    S = fmaxf(S, 1e-30f);
    const float inv = 1.0f / S;
    c += __logf(S);
#pragma unroll
    for (int u = 7; u >= 1; u--) mh[u] = mh[u - 1] * inv;
    mh[0] = m4 * inv;
    __syncthreads();
  }
}

// ---------------------------------------------------------------------------
// Final gather (one wave per b): out[b] = LSE_{k,l}(row_{len-1-k}[k,l] + T2e[l])
// row from log(els) + (log(m)+c).
// ---------------------------------------------------------------------------
__global__ __launch_bounds__(64) void final_kernel(const int* __restrict__ mask,
                                                   const float* __restrict__ Tfb_g,
                                                   const float* __restrict__ T2e_g,
                                                   const float* __restrict__ ELS,
                                                   const float* __restrict__ Mg_lin,
                                                   const float* __restrict__ cs_g,
                                                   float* __restrict__ out) {
  const int b = blockIdx.x, lane = threadIdx.x;
  int lenp = 0;
  for (int s = lane; s < S_; s += 64) lenp += (mask[b * S_ + s] == 1) ? 1 : 0;
#pragma unroll
  for (int off = 32; off > 0; off >>= 1) lenp += __shfl_xor(lenp, off);
  const int len = lenp;
  const float t2e = T2e_g[lane];
  float vals[8];
  float mx = -3.4e38f;
#pragma unroll
  for (int k = 0; k < 8; k++) {
    int tk = len - 1 - k;
    if (tk < 0) tk = S_ - 1;
    float g;
    if (k > tk) {
      g = NEGV;
    } else {
      const float elsv = ELS[((size_t)(b * S_ + tk)) * 512 + lane * 8 + k];
      const float ls = (elsv > 0.f) ? __logf(elsv) : NEGV;
      if (k == tk) {
        g = ls + Tfb_g[lane];
      } else if (mask[b * S_ + tk] == 1) {
        const int u = tk - 1 - k;
        const float mlin = Mg_lin[((size_t)b * S_ + u) * 64 + lane];
        const float M = (mlin > 0.f) ? (__logf(mlin) + cs_g[b * S_ + u]) : -1e30f;
        g = ls + M;
      } else {
        g = NEGV;
      }
    }
    const float v = g + t2e;
    vals[k] = v;
    mx = fmaxf(mx, v);
  }
#pragma unroll
  for (int off = 32; off > 0; off >>= 1) mx = fmaxf(mx, __shfl_xor(mx, off));
  float s = 0.f;
#pragma unroll
  for (int k = 0; k < 8; k++) s += __expf(vals[k] - mx);
#pragma unroll
  for (int off = 32; off > 0; off >>= 1) s += __shfl_xor(s, off);
  if (lane == 0) out[b] = __logf(s) + mx;
}

// ---------------------------------------------------------------------------
extern "C" void kernel_launch(void* const* d_in, const int* in_sizes, int n_in,
                              void* d_out, int out_size, void* d_ws, size_t ws_size,
                              hipStream_t stream) {
  const float* wr     = (const float*)d_in[0];
  const int*   mask   = (const int*)d_in[1];
  const float* conv_w = (const float*)d_in[2];
  const float* conv_b = (const float*)d_in[3];
  const float* cls_w  = (const float*)d_in[4];
  const float* cls_b  = (const float*)d_in[5];
  const float* T      = (const float*)d_in[6];
  const float* Tfb    = (const float*)d_in[7];
  const float* T2e    = (const float*)d_in[8];
  float* out = (float*)d_out;

  float* ws = (float*)d_ws;
  bf16_t* Vt    = (bf16_t*)ws;              // [512][4096] bf16  (1,048,576 f)
  bf16_t* Awr   = (bf16_t*)(ws + 1048576);  // [8192][512] bf16  (2,097,152 f)
  float*  bias2 = ws + 3145728;             // [8][64]
  float*  ELS   = ws + 3146240;             // [8192][512] fp32  (4,194,304 f)
  float*  Mg    = ws + 7340544;             // [32][256][64]     (524,288 f)
  float*  cs    = ws + 7864832;             // [32][256]         (8,192 f)
  // total 7,873,024 floats = 31.5 MB

  cast_kernel<<<2048, 256, 0, stream>>>(wr, Awr);
  w2_kernel<<<dim3(8, 8, 8), 256, 0, stream>>>(conv_w, cls_w, Vt);
  bias2_kernel<<<2, 256, 0, stream>>>(conv_b, cls_w, cls_b, bias2);
  ls_mfma<<<dim3(64, 4), 256, 0, stream>>>(Awr, Vt, bias2, mask, ELS);
  dp_kernel<<<32, 64, 0, stream>>>(T, Tfb, ELS, Mg, cs);
  final_kernel<<<32, 64, 0, stream>>>(mask, Tfb, T2e, ELS, Mg, cs, out);
}

// Round 5
// 461.778 us; speedup vs baseline: 2.0330x; 1.0903x over previous
//
#include <hip/hip_runtime.h>
#include <hip/hip_bf16.h>

#define NEGV (-10000.0f)
constexpr int B_ = 32, S_ = 256, D_ = 512, K_ = 8, L_ = 64;

typedef __bf16 bf16_t;
typedef bf16_t bf16x8 __attribute__((ext_vector_type(8)));
typedef float f32x4 __attribute__((ext_vector_type(4)));

// ---------------------------------------------------------------------------
// cast word_rep (fp32, 32*256*512) -> bf16 A matrix [8192][512]
// ---------------------------------------------------------------------------
__global__ __launch_bounds__(256) void cast_kernel(const float* __restrict__ wr,
                                                   bf16_t* __restrict__ Awr) {
  const int i = (blockIdx.x * 256 + threadIdx.x) * 8;
  const float4 a = *(const float4*)(wr + i);
  const float4 b = *(const float4*)(wr + i + 4);
  bf16x8 o;
  o[0] = (bf16_t)a.x; o[1] = (bf16_t)a.y; o[2] = (bf16_t)a.z; o[3] = (bf16_t)a.w;
  o[4] = (bf16_t)b.x; o[5] = (bf16_t)b.y; o[6] = (bf16_t)b.z; o[7] = (bf16_t)b.w;
  *(bf16x8*)(Awr + i) = o;
}

// ---------------------------------------------------------------------------
// Vt[(k*64+l)][(o*512+i)] = (k>=o) ? sum_d conv_w[k][d][i][k-o] * cls_w[l][d] : 0
// bf16, B^T layout [512][4096]. grid (8 i-tiles, 8 h, 8 k).
// ---------------------------------------------------------------------------
__global__ __launch_bounds__(256) void w2_kernel(const float* __restrict__ conv_w,
                                                 const float* __restrict__ cls_w,
                                                 bf16_t* __restrict__ Vt) {
  const int h = blockIdx.y, k = blockIdx.z;
  const int i0 = blockIdx.x * 64;
  const int tid = threadIdx.x;
  if (h > k) {  // zero-fill region o=h (>k)
    uint4 z; z.x = z.y = z.z = z.w = 0u;
#pragma unroll
    for (int q = 0; q < 2; q++) {
      const int c = tid + q * 256;
      const int l = c >> 3, cc = c & 7;
      *(uint4*)(Vt + (size_t)(k * 64 + l) * 4096 + h * 512 + i0 + cc * 8) = z;
    }
    return;
  }
  __shared__ __align__(16) float As[32 * 64];
  __shared__ __align__(16) float Bs[32 * 65];
  __shared__ __align__(16) bf16_t Ls2[64 * 72];
  float acc[16];
#pragma unroll
  for (int q = 0; q < 16; q++) acc[q] = 0.f;
  const int tr = tid >> 4, tc = tid & 15;
  for (int d0 = 0; d0 < D_; d0 += 32) {
#pragma unroll
    for (int q = 0; q < 8; q++) {
      const int dd = tid >> 3;
      const int ii = (tid & 7) * 8 + q;
      As[dd * 64 + ii] = conv_w[(size_t)((k * D_ + d0 + dd) * D_ + i0 + ii) * 8 + h];
      const int ll = tid >> 2;
      const int d2 = (tid & 3) * 8 + q;
      Bs[d2 * 65 + ll] = cls_w[ll * D_ + d0 + d2];
    }
    __syncthreads();
#pragma unroll 4
    for (int kk = 0; kk < 32; kk++) {
      float a[4], bb[4];
#pragma unroll
      for (int r = 0; r < 4; r++) a[r] = As[kk * 64 + tr * 4 + r];
#pragma unroll
      for (int c = 0; c < 4; c++) bb[c] = Bs[kk * 65 + tc * 4 + c];
#pragma unroll
      for (int r = 0; r < 4; r++)
#pragma unroll
        for (int c = 0; c < 4; c++) acc[r * 4 + c] += a[r] * bb[c];
    }
    __syncthreads();
  }
#pragma unroll
  for (int r = 0; r < 4; r++)
#pragma unroll
    for (int c = 0; c < 4; c++)
      Ls2[(tc * 4 + c) * 72 + tr * 4 + r] = (bf16_t)acc[r * 4 + c];
  __syncthreads();
  const int o = k - h;
#pragma unroll
  for (int q = 0; q < 2; q++) {
    const int c = tid + q * 256;
    const int l = c >> 3, cc = c & 7;
    const uint4 v = *(const uint4*)(&Ls2[l * 72 + cc * 8]);
    *(uint4*)(Vt + (size_t)(k * 64 + l) * 4096 + o * 512 + i0 + cc * 8) = v;
  }
}

// ---------------------------------------------------------------------------
// bias2[k][l] = cls_b[l] + sum_d conv_b[k][d] * cls_w[l][d]
// ---------------------------------------------------------------------------
__global__ void bias2_kernel(const float* __restrict__ conv_b, const float* __restrict__ cls_w,
                             const float* __restrict__ cls_b, float* __restrict__ bias2) {
  const int idx = blockIdx.x * 256 + threadIdx.x;
  const int k = idx >> 6, l = idx & 63;
  float s = cls_b[l];
  for (int d = 0; d < D_; d++) s += conv_b[k * D_ + d] * cls_w[l * D_ + d];
  bias2[idx] = s;
}

// ---------------------------------------------------------------------------
// MFMA GEMM -> ELS = exp(label_score), layout [m=8192][l*8+k].
// Strip-pair blocks (kHi=7-p, kLo=p): 144 kt-iters uniform over 256 blocks.
// ---------------------------------------------------------------------------
__global__ __launch_bounds__(256) void ls_mfma(const bf16_t* __restrict__ Awr,
                                               const bf16_t* __restrict__ Vt,
                                               const float* __restrict__ bias2,
                                               const int* __restrict__ mask,
                                               float* __restrict__ ELS) {
  constexpr int LDA = 40;
  __shared__ __align__(16) bf16_t As[128 * LDA];
  __shared__ __align__(16) bf16_t Bs[64 * LDA];
  const int tid = threadIdx.x;
  const int m0 = blockIdx.x * 128;
  const int p = blockIdx.y;
  const int w = tid >> 6, lane = tid & 63;
  const int wm = w & 1, wn = w >> 1;
  const int lrow = lane & 15, quad = lane >> 4;
  for (int s = 0; s < 2; s++) {
    const int kS = (s == 0) ? (7 - p) : p;
    const int KT = (kS + 1) * 16;
    f32x4 acc[4][2] = {};
    for (int kt = 0; kt < KT; kt++) {
      const int j0 = kt * 32;
      const int o = j0 >> 9;
      // A tile: 128 rows x 32 cols = 512 chunks of 8 bf16
#pragma unroll
      for (int q = 0; q < 2; q++) {
        const int c = tid + q * 256;
        const int row = c >> 2, cc = c & 3;
        int src = m0 + row - o;
        if (src < 0) src = 0;  // garbage feeds only t<k-masked outputs
        const uint4 va = *(const uint4*)(Awr + (size_t)src * 512 + (j0 & 511) + cc * 8);
        *(uint4*)(&As[row * LDA + cc * 8]) = va;
      }
      // B tile: 64 rows x 32 cols = 256 chunks of 8 bf16
      {
        const int br = tid >> 2, bc = tid & 3;
        const uint4 vb = *(const uint4*)(Vt + (size_t)(kS * 64 + br) * 4096 + j0 + bc * 8);
        *(uint4*)(&Bs[br * LDA + bc * 8]) = vb;
      }
      __syncthreads();
      bf16x8 af[4], bfr[2];
#pragma unroll
      for (int mi = 0; mi < 4; mi++)
        af[mi] = *(const bf16x8*)(&As[(wm * 64 + mi * 16 + lrow) * LDA + quad * 8]);
#pragma unroll
      for (int ni = 0; ni < 2; ni++)
        bfr[ni] = *(const bf16x8*)(&Bs[(wn * 32 + ni * 16 + lrow) * LDA + quad * 8]);
#pragma unroll
      for (int mi = 0; mi < 4; mi++)
#pragma unroll
        for (int ni = 0; ni < 2; ni++)
          acc[mi][ni] = __builtin_amdgcn_mfma_f32_16x16x32_bf16(af[mi], bfr[ni], acc[mi][ni], 0, 0, 0);
      __syncthreads();
    }
    // epilogue for strip kS
    float bn[2];
    int lcol[2];
#pragma unroll
    for (int ni = 0; ni < 2; ni++) {
      lcol[ni] = wn * 32 + ni * 16 + lrow;
      bn[ni] = bias2[kS * 64 + lcol[ni]];
    }
#pragma unroll
    for (int mi = 0; mi < 4; mi++) {
#pragma unroll
      for (int d = 0; d < 4; d++) {
        const int m = m0 + wm * 64 + mi * 16 + quad * 4 + d;
        const int t = m & 255;
        const bool mok = (mask[m] == 1);
#pragma unroll
        for (int ni = 0; ni < 2; ni++) {
          const float v = acc[mi][ni][d] + bn[ni];
          const float e = (!mok || t < kS || lcol[ni] == 0) ? 0.f : __expf(v);
          ELS[(size_t)m * 512 + lcol[ni] * 8 + kS] = e;
        }
      }
    }
  }
}

// ---------------------------------------------------------------------------
// Linear-domain semi-CRF DP. One wave per b; lane = label l. NO cross-lane
// shuffles: after the matvec's LDS reads every lane holds all 64 e-values,
// so S = max_j e[j] is computed redundantly per-lane from registers.
// ---------------------------------------------------------------------------
__global__ __launch_bounds__(64) void dp_kernel(const float* __restrict__ T,
                                                const float* __restrict__ Tfb_g,
                                                const float* __restrict__ ELS,
                                                float* __restrict__ Mg_lin,
                                                float* __restrict__ cs_g) {
  const int b = blockIdx.x, l = threadIdx.x;
  f32x4 rT[16];
#pragma unroll
  for (int j = 0; j < 16; j++) {
    f32x4 r;
#pragma unroll
    for (int q = 0; q < 4; q++) r[q] = __expf(T[l * 64 + j * 4 + q]);
    rT[j] = r;
  }
  __shared__ __align__(16) float eb[2][64];
  float mh[8];
  mh[0] = __expf(Tfb_g[l]);  // BEGIN phantom
#pragma unroll
  for (int u = 1; u < 8; u++) mh[u] = 0.f;
  float c = 0.f;
  const float* ep = ELS + (size_t)b * 256 * 512 + l * 8;
  float4 p0a = *(const float4*)(ep);
  float4 p0b = *(const float4*)(ep + 4);
  float4 p1a = *(const float4*)(ep + 512);
  float4 p1b = *(const float4*)(ep + 516);
  for (int t = 0; t < 256; t++) {
    const float4 ca = p0a, cb = p0b;
    p0a = p1a; p0b = p1b;
    if (t + 2 < 256) {
      p1a = *(const float4*)(ep + (size_t)(t + 2) * 512);
      p1b = *(const float4*)(ep + (size_t)(t + 2) * 512 + 4);
    }
    // e = sum_k els[k] * mh[k]
    float e0 = ca.x * mh[0] + ca.y * mh[1];
    float e1 = ca.z * mh[2] + ca.w * mh[3];
    float e2 = cb.x * mh[4] + cb.y * mh[5];
    float e3 = cb.z * mh[6] + cb.w * mh[7];
    const float e = (e0 + e1) + (e2 + e3);
    eb[t & 1][l] = e;
    // matvec + redundant per-lane max, all from the same LDS-loaded registers
    const f32x4* evp = (const f32x4*)(&eb[t & 1][0]);
    f32x4 v[16];
#pragma unroll
    for (int j = 0; j < 16; j++) v[j] = evp[j];
    f32x4 a0 = {0.f, 0.f, 0.f, 0.f}, a1 = a0, a2 = a0, a3 = a0;
    f32x4 a4 = a0, a5 = a0, a6 = a0, a7 = a0;
#pragma unroll
    for (int j = 0; j < 2; j++) {
      a0 += rT[j * 8 + 0] * v[j * 8 + 0];
      a1 += rT[j * 8 + 1] * v[j * 8 + 1];
      a2 += rT[j * 8 + 2] * v[j * 8 + 2];
      a3 += rT[j * 8 + 3] * v[j * 8 + 3];
      a4 += rT[j * 8 + 4] * v[j * 8 + 4];
      a5 += rT[j * 8 + 5] * v[j * 8 + 5];
      a6 += rT[j * 8 + 6] * v[j * 8 + 6];
      a7 += rT[j * 8 + 7] * v[j * 8 + 7];
    }
    f32x4 mx0 = v[0], mx1 = v[1], mx2 = v[2], mx3 = v[3];
#pragma unroll
    for (int j = 1; j < 4; j++) {
      mx0 = __builtin_elementwise_max(mx0, v[j * 4 + 0]);
      mx1 = __builtin_elementwise_max(mx1, v[j * 4 + 1]);
      mx2 = __builtin_elementwise_max(mx2, v[j * 4 + 2]);
      mx3 = __builtin_elementwise_max(mx3, v[j * 4 + 3]);
    }
    const f32x4 as = ((a0 + a1) + (a2 + a3)) + ((a4 + a5) + (a6 + a7));
    const float m4 = (as[0] + as[1]) + (as[2] + as[3]);
    const f32x4 mxv = __builtin_elementwise_max(__builtin_elementwise_max(mx0, mx1),
                                                __builtin_elementwise_max(mx2, mx3));
    float S = fmaxf(fmaxf(mxv[0], mxv[1]), fmaxf(mxv[2], mxv[3]));
    Mg_lin[((size_t)b * 256 + t) * 64 + l] = m4;
    if (l == 0) cs_g[b * 256 + t] = c;
    S = fmaxf(S, 1e-30f);
    const float inv = __builtin_amdgcn_rcpf(S);
    c += __logf(S);
#pragma unroll
    for (int u = 7; u >= 1; u--) mh[u] = mh[u - 1] * inv;
    mh[0] = m4 * inv;
  }
}

// ---------------------------------------------------------------------------
// Final gather (one wave per b): out[b] = LSE_{k,l}(row_{len-1-k}[k,l] + T2e[l])
// ---------------------------------------------------------------------------
__global__ __launch_bounds__(64) void final_kernel(const int* __restrict__ mask,
                                                   const float* __restrict__ Tfb_g,
                                                   const float* __restrict__ T2e_g,
                                                   const float* __restrict__ ELS,
                                                   const float* __restrict__ Mg_lin,
                                                   const float* __restrict__ cs_g,
                                                   float* __restrict__ out) {
  const int b = blockIdx.x, lane = threadIdx.x;
  int lenp = 0;
  for (int s = lane; s < S_; s += 64) lenp += (mask[b * S_ + s] == 1) ? 1 : 0;
#pragma unroll
  for (int off = 32; off > 0; off >>= 1) lenp += __shfl_xor(lenp, off);
  const int len = lenp;
  const float t2e = T2e_g[lane];
  float vals[8];
  float mx = -3.4e38f;
#pragma unroll
  for (int k = 0; k < 8; k++) {
    int tk = len - 1 - k;
    if (tk < 0) tk = S_ - 1;
    float g;
    if (k > tk) {
      g = NEGV;
    } else {
      const float elsv = ELS[((size_t)(b * S_ + tk)) * 512 + lane * 8 + k];
      const float ls = (elsv > 0.f) ? __logf(elsv) : NEGV;
      if (k == tk) {
        g = ls + Tfb_g[lane];
      } else if (mask[b * S_ + tk] == 1) {
        const int u = tk - 1 - k;
        const float mlin = Mg_lin[((size_t)b * S_ + u) * 64 + lane];
        const float M = (mlin > 0.f) ? (__logf(mlin) + cs_g[b * S_ + u]) : -1e30f;
        g = ls + M;
      } else {
        g = NEGV;
      }
    }
    const float v = g + t2e;
    vals[k] = v;
    mx = fmaxf(mx, v);
  }
#pragma unroll
  for (int off = 32; off > 0; off >>= 1) mx = fmaxf(mx, __shfl_xor(mx, off));
  float s = 0.f;
#pragma unroll
  for (int k = 0; k < 8; k++) s += __expf(vals[k] - mx);
#pragma unroll
  for (int off = 32; off > 0; off >>= 1) s += __shfl_xor(s, off);
  if (lane == 0) out[b] = __logf(s) + mx;
}

// ---------------------------------------------------------------------------
extern "C" void kernel_launch(void* const* d_in, const int* in_sizes, int n_in,
                              void* d_out, int out_size, void* d_ws, size_t ws_size,
                              hipStream_t stream) {
  const float* wr     = (const float*)d_in[0];
  const int*   mask   = (const int*)d_in[1];
  const float* conv_w = (const float*)d_in[2];
  const float* conv_b = (const float*)d_in[3];
  const float* cls_w  = (const float*)d_in[4];
  const float* cls_b  = (const float*)d_in[5];
  const float* T      = (const float*)d_in[6];
  const float* Tfb    = (const float*)d_in[7];
  const float* T2e    = (const float*)d_in[8];
  float* out = (float*)d_out;

  float* ws = (float*)d_ws;
  bf16_t* Vt    = (bf16_t*)ws;              // [512][4096] bf16  (1,048,576 f)
  bf16_t* Awr   = (bf16_t*)(ws + 1048576);  // [8192][512] bf16  (2,097,152 f)
  float*  bias2 = ws + 3145728;             // [8][64]
  float*  ELS   = ws + 3146240;             // [8192][512] fp32  (4,194,304 f)
  float*  Mg    = ws + 7340544;             // [32][256][64]     (524,288 f)
  float*  cs    = ws + 7864832;             // [32][256]         (8,192 f)
  // total 7,873,024 floats = 31.5 MB

  cast_kernel<<<2048, 256, 0, stream>>>(wr, Awr);
  w2_kernel<<<dim3(8, 8, 8), 256, 0, stream>>>(conv_w, cls_w, Vt);
  bias2_kernel<<<2, 256, 0, stream>>>(conv_b, cls_w, cls_b, bias2);
  ls_mfma<<<dim3(64, 4), 256, 0, stream>>>(Awr, Vt, bias2, mask, ELS);
  dp_kernel<<<32, 64, 0, stream>>>(T, Tfb, ELS, Mg, cs);
  final_kernel<<<32, 64, 0, stream>>>(mask, Tfb, T2e, ELS, Mg, cs, out);
}